// Round 1
// 1118.814 us; speedup vs baseline: 1.3029x; 1.3029x over previous
//
#include <hip/hip_runtime.h>
#include <cmath>

// ---------------------------------------------------------------------------
// PhrasalScaledDotProductAttention on MI355X (gfx950)
// Pipeline:
//  1) cast fp32 -> f16 (queries split hi/lo for high-precision P chain)
//  2) Q/K/V projections: f16 MFMA NT-GEMM (B^T = weight rows), f16 out
//  3) V transpose -> Vt[b,h,d,n] for att@V B-operand
//  4) xW = q @ Wb   : split-f16 (3-MFMA) GEMM, split f16 output
//  5) Plogit = xW @ q^T per batch: split-f16 GEMM, epilogue sigmoid -> P (out)
//     and Lp_r = 8*lam*log(P+1e-9) fp32 (ws), layout [b][q>>2][k][q&3] so the
//     attention kernels can acc-init each MFMA tile with one f32x4 load/lane.
//  6) attention, two lean kernels (no max-tracking; logits bounded ~16):
//     pass1: QK^T (acc-init = 8*lam*Lp) -> l = sum exp(s/8... see code) -> linv
//            (double-buffered K staging, 1 barrier per kt)
//     pass2: QK^T again in k-quarters, att = exp(.)*linv -> global,
//            att(f16) -> small swizzled LDS -> PV MFMA -> Obf
//  7) out = O @ Wo^T + bo : f16 MFMA GEMM, fp32 out
// Workspace: 156 MB (aliased; linv reuses the q_hi region).
// ---------------------------------------------------------------------------

typedef _Float16 f16;
typedef _Float16 f16x8 __attribute__((ext_vector_type(8)));
typedef _Float16 f16x4 __attribute__((ext_vector_type(4)));
typedef float    f32x4 __attribute__((ext_vector_type(4)));

#define DEVI __device__ __forceinline__

DEVI void async16(const void* g, void* l) {
    // global -> LDS direct copy, 16B/lane. LDS dest = wave-uniform base + lane*16.
    __builtin_amdgcn_global_load_lds((const __attribute__((address_space(1))) unsigned int*)g,
                                     (__attribute__((address_space(3))) unsigned int*)l,
                                     16, 0, 0);
}

// ---------------- casts -----------------------------------------------------

__global__ __launch_bounds__(256) void cast_qkv(
        const float* __restrict__ q, const float* __restrict__ k, const float* __restrict__ v,
        f16* __restrict__ qh, f16* __restrict__ ql, f16* __restrict__ kh, f16* __restrict__ vh)
{
    size_t i = ((size_t)blockIdx.x * 256 + threadIdx.x) * 4;
    f32x4 qv = *(const f32x4*)(q + i);
    f32x4 kv = *(const f32x4*)(k + i);
    f32x4 vv = *(const f32x4*)(v + i);
    f16x4 a, b, c, d;
#pragma unroll
    for (int j = 0; j < 4; ++j) {
        f16 h = (f16)qv[j];
        a[j] = h;
        b[j] = (f16)(qv[j] - (float)h);
        c[j] = (f16)kv[j];
        d[j] = (f16)vv[j];
    }
    *(f16x4*)(qh + i) = a;
    *(f16x4*)(ql + i) = b;
    *(f16x4*)(kh + i) = c;
    *(f16x4*)(vh + i) = d;
}

__global__ __launch_bounds__(256) void cast_w(
        const float* __restrict__ w0, const float* __restrict__ w1,
        const float* __restrict__ w2, const float* __restrict__ w3,
        f16* __restrict__ o0, f16* __restrict__ o1, f16* __restrict__ o2, f16* __restrict__ o3)
{
    size_t i = ((size_t)blockIdx.x * 256 + threadIdx.x) * 4;
    f32x4 a = *(const f32x4*)(w0 + i);
    f32x4 b = *(const f32x4*)(w1 + i);
    f32x4 c = *(const f32x4*)(w2 + i);
    f32x4 d = *(const f32x4*)(w3 + i);
    f16x4 ra, rb, rc, rd;
#pragma unroll
    for (int j = 0; j < 4; ++j) { ra[j] = (f16)a[j]; rb[j] = (f16)b[j]; rc[j] = (f16)c[j]; rd[j] = (f16)d[j]; }
    *(f16x4*)(o0 + i) = ra;
    *(f16x4*)(o1 + i) = rb;
    *(f16x4*)(o2 + i) = rc;
    *(f16x4*)(o3 + i) = rd;
}

// Wb[d][o] -> Wbt_hi/lo[o][d] (transpose + hi/lo split)
__global__ __launch_bounds__(256) void wb_trans(const float* __restrict__ Wb,
                                                f16* __restrict__ Th, f16* __restrict__ Tl)
{
    __shared__ float tile[64][65];
    const int to = blockIdx.x, td = blockIdx.y, t = threadIdx.x;
#pragma unroll
    for (int it = 0; it < 16; ++it) {
        int e = it * 256 + t;
        int d = e >> 6, o = e & 63;
        tile[o][d] = Wb[(size_t)(td * 64 + d) * 1024 + to * 64 + o];
    }
    __syncthreads();
#pragma unroll
    for (int it = 0; it < 16; ++it) {
        int e = it * 256 + t;
        int o = e >> 6, d = e & 63;
        float v = tile[o][d];
        f16 h = (f16)v;
        size_t idx = (size_t)(to * 64 + o) * 1024 + td * 64 + d;
        Th[idx] = h;
        Tl[idx] = (f16)(v - (float)h);
    }
}

// Vb[b][n][h*64+d] -> Vt[(b*16+h)][d][n]
__global__ __launch_bounds__(256) void v_trans(const f16* __restrict__ Vb, f16* __restrict__ Vt)
{
    __shared__ f16 tile[64][72];
    const int nt = blockIdx.x, bh = blockIdx.y, t = threadIdx.x;
    const int b = bh >> 4, h = bh & 15;
#pragma unroll
    for (int it = 0; it < 16; ++it) {
        int e = it * 256 + t;
        int n = e >> 6, d = e & 63;
        tile[d][n] = Vb[((size_t)(b * 1024 + nt * 64 + n)) * 1024 + h * 64 + d];
    }
    __syncthreads();
#pragma unroll
    for (int it = 0; it < 16; ++it) {
        int e = it * 256 + t;
        int d = e >> 6, n = e & 63;
        Vt[((size_t)bh * 64 + d) * 1024 + nt * 64 + n] = tile[d][n];
    }
}

// ---------------- plain f16 NT GEMM: C[M,N] = A[M,K] @ B[N,K]^T + bias ------
// MODE 0: fp32 out ; MODE 1: f16 out. 128x128 tile, BK=64, 4 waves (2x2).
template<int MODE>
__global__ __launch_bounds__(256) void gemm_nt(
        const f16* __restrict__ A, const f16* __restrict__ B,
        const float* __restrict__ bias, void* __restrict__ Cout,
        int M, int N, int K, size_t sA, size_t sB, size_t sC)
{
    __shared__ __align__(16) f16 As[128 * 64];
    __shared__ __align__(16) f16 Bs[128 * 64];
    const int tid = threadIdx.x;
    const int lane = tid & 63;
    const int w = tid >> 6;
    const int wq = w >> 1, wn = w & 1;
    const int l15 = lane & 15, q4 = lane >> 4;
    const size_t z = blockIdx.z;
    const f16* Ab = A + z * sA;
    const f16* Bb = B + z * sB;
    const int tm = blockIdx.y * 128, tn = blockIdx.x * 128;
    const int srow = tid >> 3;
    const int scol = ((tid & 7) ^ (srow & 7)) << 3;   // XOR swizzle (global side)

    f32x4 acc[4][4] = {};

    for (int k0 = 0; k0 < K; k0 += 64) {
#pragma unroll
        for (int c = 0; c < 4; ++c) {
            int r = (c << 5) + srow;
            async16(Ab + (size_t)(tm + r) * K + k0 + scol, &As[c * 2048 + tid * 8]);
            async16(Bb + (size_t)(tn + r) * K + k0 + scol, &Bs[c * 2048 + tid * 8]);
        }
        __syncthreads();
#pragma unroll
        for (int ks = 0; ks < 2; ++ks) {
            f16x8 af[4], bf[4];
#pragma unroll
            for (int i = 0; i < 4; ++i) {
                int m = wq * 64 + i * 16 + l15;
                af[i] = *(const f16x8*)&As[m * 64 + ((((ks << 2) + q4) ^ (m & 7)) << 3)];
                int n = wn * 64 + i * 16 + l15;
                bf[i] = *(const f16x8*)&Bs[n * 64 + ((((ks << 2) + q4) ^ (n & 7)) << 3)];
            }
#pragma unroll
            for (int mi = 0; mi < 4; ++mi)
#pragma unroll
                for (int ni = 0; ni < 4; ++ni)
                    acc[mi][ni] = __builtin_amdgcn_mfma_f32_16x16x32_f16(af[mi], bf[ni], acc[mi][ni], 0, 0, 0);
        }
        __syncthreads();
    }

#pragma unroll
    for (int mi = 0; mi < 4; ++mi)
#pragma unroll
        for (int ni = 0; ni < 4; ++ni) {
            const int col = tn + wn * 64 + ni * 16 + l15;
            const float bv = bias[col];
#pragma unroll
            for (int r = 0; r < 4; ++r) {
                const int row = tm + wq * 64 + mi * 16 + q4 * 4 + r;
                const float v = acc[mi][ni][r] + bv;
                const size_t idx = z * sC + (size_t)row * N + col;
                if (MODE == 0) ((float*)Cout)[idx] = v;
                else           ((f16*)Cout)[idx] = (f16)v;
            }
        }
}

// ---------------- split-f16 (hi/lo) NT GEMM, 3 MFMAs per tile ----------------
// MODE 0: write split pair (f16 hi, f16 lo). MODE 1: P = sigmoid(c + bb), write
// P (fp32, out0) and Lp_r = 8*lam*log(P+1e-9) (fp32, out1) in permuted layout
// [b][q>>2][k][q&3] (f32x4 stores). BK=32.
template<int MODE>
__global__ __launch_bounds__(256) void gemm_nt3(
        const f16* __restrict__ Ah, const f16* __restrict__ Al,
        const f16* __restrict__ Bh, const f16* __restrict__ Bl,
        void* __restrict__ out0, void* __restrict__ out1,
        const float* __restrict__ bbp, const float* __restrict__ lamp,
        int M, int N, int K, size_t sA, size_t sB, size_t sC)
{
    __shared__ __align__(16) f16 Ash[128 * 32], Asl[128 * 32], Bsh[128 * 32], Bsl[128 * 32];
    const int tid = threadIdx.x;
    const int lane = tid & 63;
    const int w = tid >> 6;
    const int wq = w >> 1, wn = w & 1;
    const int l15 = lane & 15, q4 = lane >> 4;
    const size_t z = blockIdx.z;
    const f16* Ahb = Ah + z * sA; const f16* Alb = Al + z * sA;
    const f16* Bhb = Bh + z * sB; const f16* Blb = Bl + z * sB;
    const int tm = blockIdx.y * 128, tn = blockIdx.x * 128;
    const int srow = tid >> 2;
    const int scol = ((tid & 3) ^ (srow & 3)) << 3;

    f32x4 acc[4][4] = {};

    for (int k0 = 0; k0 < K; k0 += 32) {
#pragma unroll
        for (int c = 0; c < 2; ++c) {
            int r = (c << 6) + srow;
            const size_t ga = (size_t)(tm + r) * K + k0 + scol;
            const size_t gb = (size_t)(tn + r) * K + k0 + scol;
            async16(Ahb + ga, &Ash[c * 2048 + tid * 8]);
            async16(Alb + ga, &Asl[c * 2048 + tid * 8]);
            async16(Bhb + gb, &Bsh[c * 2048 + tid * 8]);
            async16(Blb + gb, &Bsl[c * 2048 + tid * 8]);
        }
        __syncthreads();
        f16x8 ah[4], al[4], bh[4], bl[4];
#pragma unroll
        for (int i = 0; i < 4; ++i) {
            int m = wq * 64 + i * 16 + l15;
            int offa = m * 32 + ((q4 ^ (m & 3)) << 3);
            ah[i] = *(const f16x8*)&Ash[offa];
            al[i] = *(const f16x8*)&Asl[offa];
            int n = wn * 64 + i * 16 + l15;
            int offb = n * 32 + ((q4 ^ (n & 3)) << 3);
            bh[i] = *(const f16x8*)&Bsh[offb];
            bl[i] = *(const f16x8*)&Bsl[offb];
        }
#pragma unroll
        for (int mi = 0; mi < 4; ++mi)
#pragma unroll
            for (int ni = 0; ni < 4; ++ni) {
                acc[mi][ni] = __builtin_amdgcn_mfma_f32_16x16x32_f16(ah[mi], bh[ni], acc[mi][ni], 0, 0, 0);
                acc[mi][ni] = __builtin_amdgcn_mfma_f32_16x16x32_f16(ah[mi], bl[ni], acc[mi][ni], 0, 0, 0);
                acc[mi][ni] = __builtin_amdgcn_mfma_f32_16x16x32_f16(al[mi], bh[ni], acc[mi][ni], 0, 0, 0);
            }
        __syncthreads();
    }

    float bb0 = 0.f, l8 = 0.f;
    if constexpr (MODE == 1) { bb0 = bbp[0]; l8 = 8.f * lamp[0]; }
#pragma unroll
    for (int mi = 0; mi < 4; ++mi)
#pragma unroll
        for (int ni = 0; ni < 4; ++ni) {
            const int row0 = tm + wq * 64 + mi * 16 + q4 * 4;
            const int col = tn + wn * 64 + ni * 16 + l15;
            if constexpr (MODE == 0) {
#pragma unroll
                for (int r = 0; r < 4; ++r) {
                    const size_t idx = z * sC + (size_t)(row0 + r) * N + col;
                    float v = acc[mi][ni][r];
                    f16 hi = (f16)v;
                    ((f16*)out0)[idx] = hi;
                    ((f16*)out1)[idx] = (f16)(v - (float)hi);
                }
            } else {
                f32x4 lpv;
#pragma unroll
                for (int r = 0; r < 4; ++r) {
                    float zt = acc[mi][ni][r] + bb0;
                    zt = fminf(fmaxf(zt, -87.f), 87.f);   // avoid inf under fast-math
                    float Pv = 1.f / (1.f + expf(-zt));
                    ((float*)out0)[z * sC + (size_t)(row0 + r) * N + col] = Pv;
                    lpv[r] = l8 * logf(Pv + 1e-9f);
                }
                // permuted Lp: float offset = z*sC + (q>>2)*4096 + k*4 + (q&3)
                *(f32x4*)&((float*)out1)[z * sC + (size_t)(row0 >> 2) * 4096 + (size_t)col * 4] = lpv;
            }
        }
}

// ---------------- attention pass 1: linv = 1 / sum_k exp(s) -----------------
// grid (qt=8, h=16, b=8), 256 threads. Wave w: q rows [w*32, w*32+32), all k.
// No max-tracking: s = (qk + 8*lam*log(P+eps)) * 0.125, |s| bounded (~16) so
// fp32 exp is safe. K staging is double-buffered: one barrier per kt.
__global__ __launch_bounds__(256) void attn_pass1(
        const f16* __restrict__ Qf, const f16* __restrict__ Kf,
        const float* __restrict__ Lp, float* __restrict__ linv)
{
    __shared__ __align__(16) f16 Ks[2][128 * 64];   // 32 KB

    const int qt = blockIdx.x, h = blockIdx.y, b = blockIdx.z;
    const int tid = threadIdx.x, lane = tid & 63, w = tid >> 6;
    const int l15 = lane & 15, q4 = lane >> 4;

    f16x8 aq[2][2];
    const size_t qbase = ((size_t)(b * 1024 + qt * 128 + w * 32)) * 1024 + h * 64;
#pragma unroll
    for (int mi = 0; mi < 2; ++mi)
#pragma unroll
        for (int ks = 0; ks < 2; ++ks)
            aq[mi][ks] = *(const f16x8*)&Qf[qbase + (size_t)(mi * 16 + l15) * 1024 + ks * 32 + q4 * 8];

    const size_t kgbase = ((size_t)b * 1024) * 1024 + h * 64;
    const int srow = tid >> 3;
    const int scol = ((tid & 7) ^ (srow & 7)) << 3;
    // Lp_r base for this lane's row-quads: qg = qt*32 + w*8 + mi*4 + q4
    const size_t lpb = (size_t)b * 1048576 + (size_t)(qt * 32 + w * 8 + q4) * 4096;

    float lsum[8];
#pragma unroll
    for (int i = 0; i < 8; ++i) lsum[i] = 0.f;

    // prologue: stage kt=0 into buf 0
#pragma unroll
    for (int c = 0; c < 4; ++c) {
        int r = (c << 5) + srow;
        async16(&Kf[kgbase + (size_t)r * 1024 + scol], &Ks[0][c * 2048 + tid * 8]);
    }
    __syncthreads();

    int cur = 0;
    for (int kt = 0; kt < 8; ++kt) {
        if (kt < 7) {
#pragma unroll
            for (int c = 0; c < 4; ++c) {
                int r = (c << 5) + srow;
                async16(&Kf[kgbase + (size_t)((kt + 1) * 128 + r) * 1024 + scol],
                        &Ks[cur ^ 1][c * 2048 + tid * 8]);
            }
        }
        // acc init = 8*lam*log(P+eps), one f32x4 per (mi,ni)
        f32x4 sc[2][8];
#pragma unroll
        for (int mi = 0; mi < 2; ++mi)
#pragma unroll
            for (int ni = 0; ni < 8; ++ni)
                sc[mi][ni] = *(const f32x4*)&Lp[lpb + (size_t)mi * 16384 +
                                                (size_t)(kt * 128 + ni * 16 + l15) * 4];
#pragma unroll
        for (int ks = 0; ks < 2; ++ks)
#pragma unroll
            for (int ni = 0; ni < 8; ++ni) {
                int n = ni * 16 + l15;
                f16x8 bf = *(const f16x8*)&Ks[cur][n * 64 + ((((ks << 2) + q4) ^ (n & 7)) << 3)];
#pragma unroll
                for (int mi = 0; mi < 2; ++mi)
                    sc[mi][ni] = __builtin_amdgcn_mfma_f32_16x16x32_f16(aq[mi][ks], bf, sc[mi][ni], 0, 0, 0);
            }
#pragma unroll
        for (int mi = 0; mi < 2; ++mi)
#pragma unroll
            for (int r2 = 0; r2 < 4; ++r2) {
                float s = 0.f;
#pragma unroll
                for (int ni = 0; ni < 8; ++ni) s += __expf(sc[mi][ni][r2] * 0.125f);
                lsum[mi * 4 + r2] += s;
            }
        __syncthreads();   // drains next-tile staging (issued before compute)
        cur ^= 1;
    }

#pragma unroll
    for (int i = 0; i < 8; ++i) {
        float s = lsum[i];
        s += __shfl_xor(s, 1, 16);
        s += __shfl_xor(s, 2, 16);
        s += __shfl_xor(s, 4, 16);
        s += __shfl_xor(s, 8, 16);
        lsum[i] = s;
    }
    if (l15 == 0) {
        const size_t ob = ((size_t)(b * 16 + h)) * 1024 + qt * 128 + w * 32;
#pragma unroll
        for (int mi = 0; mi < 2; ++mi)
#pragma unroll
            for (int r2 = 0; r2 < 4; ++r2)
                linv[ob + mi * 16 + q4 * 4 + r2] = 1.f / lsum[mi * 4 + r2];
    }
}

// ---------------- attention pass 2: att out + O accumulate ------------------
// QK^T recomputed in k-quarters (sc = 16 VGPRs); att = exp(s)*linv written to
// global and to a small per-wave swizzled LDS buffer feeding the PV MFMA.
// LDS = 16 (Ks) + 16 (Vs) + 8 (atts) = 40 KB.
__global__ __launch_bounds__(256) void attn_pass2(
        const f16* __restrict__ Qf, const f16* __restrict__ Kf,
        const f16* __restrict__ Vt, const float* __restrict__ Lp,
        const float* __restrict__ linv,
        float* __restrict__ att, f16* __restrict__ Obf)
{
    __shared__ __align__(16) f16 Ks[128 * 64];      // 16 KB, swizzled (8 blk/row)
    __shared__ __align__(16) f16 Vs[64 * 128];      // 16 KB, swizzled (16 blk/row)
    __shared__ __align__(16) f16 atts[4][32 * 32];  // 8 KB, per-wave quarter tiles

    const int qt = blockIdx.x, h = blockIdx.y, b = blockIdx.z;
    const int tid = threadIdx.x, lane = tid & 63, w = tid >> 6;
    const int l15 = lane & 15, q4 = lane >> 4;

    f16x8 aq[2][2];
    const size_t qbase = ((size_t)(b * 1024 + qt * 128 + w * 32)) * 1024 + h * 64;
#pragma unroll
    for (int mi = 0; mi < 2; ++mi)
#pragma unroll
        for (int ks = 0; ks < 2; ++ks)
            aq[mi][ks] = *(const f16x8*)&Qf[qbase + (size_t)(mi * 16 + l15) * 1024 + ks * 32 + q4 * 8];

    float inv_l[8];
    {
        const size_t lb = ((size_t)(b * 16 + h)) * 1024 + qt * 128 + w * 32;
        f32x4 iv0 = *(const f32x4*)&linv[lb + q4 * 4];
        f32x4 iv1 = *(const f32x4*)&linv[lb + 16 + q4 * 4];
#pragma unroll
        for (int r = 0; r < 4; ++r) { inv_l[r] = iv0[r]; inv_l[4 + r] = iv1[r]; }
    }

    const size_t kgbase = ((size_t)b * 1024) * 1024 + h * 64;
    const size_t lpb = (size_t)b * 1048576 + (size_t)(qt * 32 + w * 8 + q4) * 4096;
    const size_t attbase = ((size_t)((b * 16 + h) * 1024 + qt * 128 + w * 32)) * 1024;
    const int srow = tid >> 3;
    const int scol = ((tid & 7) ^ (srow & 7)) << 3;
    const int vr0 = tid >> 4;
    const int vcb = ((tid & 15) ^ vr0) << 3;

    f32x4 oacc[2][4] = {};
    f16* atts_w = &atts[w][0];

    for (int kt = 0; kt < 8; ++kt) {
#pragma unroll
        for (int c = 0; c < 4; ++c) {
            int r = (c << 5) + srow;
            async16(&Kf[kgbase + (size_t)(kt * 128 + r) * 1024 + scol], &Ks[c * 2048 + tid * 8]);
            int vr = (c << 4) + vr0;
            async16(&Vt[((size_t)(b * 16 + h) * 64 + vr) * 1024 + kt * 128 + vcb], &Vs[c * 2048 + tid * 8]);
        }
        __syncthreads();
#pragma unroll
        for (int qx = 0; qx < 4; ++qx) {
            // acc init from permuted Lp (f32x4 per (mi,nq))
            f32x4 sc[2][2];
#pragma unroll
            for (int mi = 0; mi < 2; ++mi)
#pragma unroll
                for (int nq = 0; nq < 2; ++nq)
                    sc[mi][nq] = *(const f32x4*)&Lp[lpb + (size_t)mi * 16384 +
                                  (size_t)(kt * 128 + qx * 32 + nq * 16 + l15) * 4];
#pragma unroll
            for (int ks = 0; ks < 2; ++ks)
#pragma unroll
                for (int nq = 0; nq < 2; ++nq) {
                    int n = qx * 32 + nq * 16 + l15;
                    f16x8 bf = *(const f16x8*)&Ks[n * 64 + ((((ks << 2) + q4) ^ (n & 7)) << 3)];
#pragma unroll
                    for (int mi = 0; mi < 2; ++mi)
                        sc[mi][nq] = __builtin_amdgcn_mfma_f32_16x16x32_f16(aq[mi][ks], bf, sc[mi][nq], 0, 0, 0);
                }
            // epilogue: att -> global + swizzled per-wave LDS (f16)
            // quarter-tile swizzle: seg' = seg ^ ((row>>1)&3)  (2-way free on read)
#pragma unroll
            for (int mi = 0; mi < 2; ++mi)
#pragma unroll
                for (int r2 = 0; r2 < 4; ++r2) {
                    const int ri = mi * 4 + r2;
                    const int qrl = mi * 16 + q4 * 4 + r2;
                    float* attq = &att[attbase + (size_t)qrl * 1024 + kt * 128 + qx * 32];
#pragma unroll
                    for (int nq = 0; nq < 2; ++nq) {
                        const int lc = nq * 16 + l15;
                        float a = __expf(sc[mi][nq][r2] * 0.125f) * inv_l[ri];
                        attq[lc] = a;
                        atts_w[qrl * 32 + (((lc >> 3) ^ ((qrl >> 1) & 3)) << 3) + (lc & 7)] = (f16)a;
                    }
                }
            // PV for this k-quarter (same-wave LDS write->read: DS pipe in-order)
            f16x8 av[2];
#pragma unroll
            for (int mi = 0; mi < 2; ++mi) {
                int m = mi * 16 + l15;
                av[mi] = *(const f16x8*)&atts_w[m * 32 + ((q4 ^ ((m >> 1) & 3)) << 3)];
            }
#pragma unroll
            for (int nv = 0; nv < 4; ++nv) {
                int n = nv * 16 + l15;
                f16x8 bv = *(const f16x8*)&Vs[n * 128 + (((qx * 4 + q4) ^ (n & 15)) << 3)];
#pragma unroll
                for (int mi = 0; mi < 2; ++mi)
                    oacc[mi][nv] = __builtin_amdgcn_mfma_f32_16x16x32_f16(av[mi], bv, oacc[mi][nv], 0, 0, 0);
            }
        }
        __syncthreads();
    }

#pragma unroll
    for (int mi = 0; mi < 2; ++mi)
#pragma unroll
        for (int nv = 0; nv < 4; ++nv)
#pragma unroll
            for (int r2 = 0; r2 < 4; ++r2) {
                const size_t row = (size_t)(b * 1024 + qt * 128 + w * 32 + mi * 16 + q4 * 4 + r2);
                Obf[row * 1024 + h * 64 + nv * 16 + l15] = (f16)oacc[mi][nv][r2];
            }
}

// ---------------------------------------------------------------------------

extern "C" void kernel_launch(void* const* d_in, const int* in_sizes, int n_in,
                              void* d_out, int out_size, void* d_ws, size_t ws_size,
                              hipStream_t stream)
{
    (void)in_sizes; (void)n_in; (void)out_size; (void)ws_size;

    const float* queries = (const float*)d_in[0];
    const float* keys    = (const float*)d_in[1];
    const float* values  = (const float*)d_in[2];
    const float* Wq = (const float*)d_in[3];
    const float* bq = (const float*)d_in[4];
    const float* Wk = (const float*)d_in[5];
    const float* bk = (const float*)d_in[6];
    const float* Wv = (const float*)d_in[7];
    const float* bv = (const float*)d_in[8];
    const float* Wo = (const float*)d_in[9];
    const float* bo = (const float*)d_in[10];
    const float* Wb = (const float*)d_in[11];
    const float* bb = (const float*)d_in[12];
    const float* lam = (const float*)d_in[13];

    float* out  = (float*)d_out;                      // [8,1024,1024]
    float* attO = out + (size_t)8 * 1024 * 1024;      // [8,16,1024,1024]
    float* POut = attO + (size_t)8 * 16 * 1024 * 1024;// [8,1024,1024]

    char* ws = (char*)d_ws;
    const size_t MB = 1024 * 1024;
    // workspace map (aliased; total 156 MB):
    f16*  q_hi = (f16*)(ws + 0 * MB);     // queries hi; linv aliases after P-GEMM
    f16*  q_lo = (f16*)(ws + 16 * MB);    // queries lo; Obf aliases after P-GEMM
    f16*  k_h  = (f16*)(ws + 32 * MB);    // keys f16; xw_hi aliases after K-GEMM
    f16*  v_h  = (f16*)(ws + 48 * MB);    // values f16; xw_lo aliases after V-GEMM
    f16*  Qb   = (f16*)(ws + 64 * MB);
    f16*  Kb   = (f16*)(ws + 80 * MB);
    f16*  Vt   = (f16*)(ws + 96 * MB);
    float* Lp  = (float*)(ws + 112 * MB); // fp32 [8M], permuted Lp_r; Vb aliases
    f16*  Vb   = (f16*)(ws + 112 * MB);   // V projection pre-transpose
    f16*  cWq  = (f16*)(ws + 144 * MB);
    f16*  cWk  = cWq + 1024 * 1024;
    f16*  cWv  = cWk + 1024 * 1024;
    f16*  cWo  = cWv + 1024 * 1024;
    f16*  Wbt_h = cWo + 1024 * 1024;
    f16*  Wbt_l = Wbt_h + 1024 * 1024;
    f16*  xw_h = k_h;            // reuse after K projection
    f16*  xw_l = v_h;            // reuse after V projection
    f16*  Obf  = q_lo;           // reuse after P GEMM
    float* linv = (float*)q_hi;  // reuse after P GEMM (512 KB)

    const size_t S1M = (size_t)1024 * 1024;

    cast_qkv<<<8192, 256, 0, stream>>>(queries, keys, values, q_hi, q_lo, k_h, v_h);
    cast_w<<<1024, 256, 0, stream>>>(Wq, Wk, Wv, Wo, cWq, cWk, cWv, cWo);
    wb_trans<<<dim3(16, 16), 256, 0, stream>>>(Wb, Wbt_h, Wbt_l);

    gemm_nt<1><<<dim3(8, 64), 256, 0, stream>>>(q_hi, cWq, bq, Qb, 8192, 1024, 1024, 0, 0, 0);
    gemm_nt<1><<<dim3(8, 64), 256, 0, stream>>>(k_h,  cWk, bk, Kb, 8192, 1024, 1024, 0, 0, 0);
    gemm_nt<1><<<dim3(8, 64), 256, 0, stream>>>(v_h,  cWv, bv, Vb, 8192, 1024, 1024, 0, 0, 0);
    v_trans<<<dim3(16, 128), 256, 0, stream>>>(Vb, Vt);

    // xW = queries @ Wb  (split precision), split output
    gemm_nt3<0><<<dim3(8, 64), 256, 0, stream>>>(q_hi, q_lo, Wbt_h, Wbt_l,
                                                 xw_h, xw_l, nullptr, nullptr,
                                                 8192, 1024, 1024, 0, 0, 0);
    // Plogit = xW @ queries^T per batch -> P (output) + permuted Lp_r (ws)
    gemm_nt3<1><<<dim3(8, 8, 8), 256, 0, stream>>>(xw_h, xw_l, q_hi, q_lo,
                                                   POut, Lp, bb, lam,
                                                   1024, 1024, 1024, S1M, S1M, S1M);

    attn_pass1<<<dim3(8, 16, 8), 256, 0, stream>>>(Qb, Kb, Lp, linv);
    attn_pass2<<<dim3(8, 16, 8), 256, 0, stream>>>(Qb, Kb, Vt, Lp, linv, attO, Obf);

    gemm_nt<0><<<dim3(8, 64), 256, 0, stream>>>(Obf, cWo, bo, out, 8192, 1024, 1024, 0, 0, 0);
}